// Round 8
// baseline (396.173 us; speedup 1.0000x reference)
//
#include <hip/hip_runtime.h>

// x[2,8,540,960] f32, filt[16,8] f32, scale=3 (runtime), out[2,8,1620,2880] f32.
#define Hh 540
#define Ww 960
#define OHh 1620
#define OWw 2880
#define OW4 720          // float4 groups per output row
#define RPB 60           // rows per block; 1620 = 27 * 60

typedef float floatx4 __attribute__((ext_vector_type(4)));

// Thread owns 4 fixed output columns; loops over RPB rows. Row-invariant work
// (column phases, x loads, horizontal collapse) hoisted; row weights preloaded
// to registers; steady-state row body = 4 mults + coalesced 16B store.
__global__ __launch_bounds__(256) void vtm_upsample(
    const float* __restrict__ x, const float* __restrict__ filt,
    const int* __restrict__ scale_p, float* __restrict__ out)
{
    __shared__ float s_f[16][8];
    __shared__ float s_sum[16];
    __shared__ float s_wy[RPB];      // s_sum[fy] * (1/4096) per row
    __shared__ unsigned s_rm[RPB];   // r0 | fy<<10 | sat<<14 | (iy+8)<<15

    const int tid = threadIdx.x;
    const unsigned scale = (unsigned)*scale_p;
    const float inv = 1.0f / 4096.0f;
    const unsigned oy0 = blockIdx.y * RPB;

    if (tid < 128) ((float*)s_f)[tid] = filt[tid];
    __syncthreads();
    if (tid < 16) {
        float s = 0.f;
        #pragma unroll
        for (int k = 0; k < 8; ++k) s += s_f[tid][k];  // same order as prior passing rounds
        s_sum[tid] = s;
    }
    __syncthreads();
    if (tid < RPB) {
        // Row phase: ref=int(oy*16384/scale); integer=ref>>4; frac=ref&15 (u32 math).
        const unsigned oy = oy0 + (unsigned)tid;
        const unsigned ref = (oy * 16384u) / scale;
        const int ii = (int)(ref >> 4);
        const unsigned f = ref & 15u;
        const int lo = min(max(ii - 3, 0), Hh - 1);
        const int hi = min(max(ii + 4, 0), Hh - 1);
        s_rm[tid] = (unsigned)lo | (f << 10) | ((lo == hi) ? 0x4000u : 0u)
                  | ((unsigned)(min(max(ii, -8), 4095) + 8) << 15);
        s_wy[tid] = s_sum[f] * inv;
    }
    __syncthreads();

    const unsigned bc = blockIdx.z;
    const float* __restrict__ xp = x + (size_t)bc * (Hh * Ww);
    float* __restrict__ op = out + (size_t)bc * ((size_t)OHh * OWw);
    const unsigned g = blockIdx.x * 256u + (unsigned)tid;
    if (g >= OW4) return;            // no barriers below this point

    // ---- Row-invariant column setup (once per thread) ----
    float vx[4];                     // row-H-1-collapsed value * wx (saturated rows)
    int   ixs[4], fxs[4];
    {
        const float* __restrict__ rp = xp + (Hh - 1) * Ww;
        #pragma unroll
        for (int u = 0; u < 4; ++u) {
            const unsigned ox = 4u * g + (unsigned)u;
            const unsigned refx = (ox * 16384u) / scale;
            const int ix = (int)(refx >> 4);
            const int fx = (int)(refx & 15u);
            ixs[u] = ix; fxs[u] = fx;
            const int c0 = min(max(ix - 3, 0), Ww - 1);
            const int c7 = min(max(ix + 4, 0), Ww - 1);
            if (c0 == c7) {
                vx[u] = rp[c0] * s_sum[fx];            // horizontal 8-tap collapses
            } else {
                float h = 0.f;                          // rare: ox<3 — real horizontal MAC
                #pragma unroll
                for (int k = 0; k < 8; ++k) {
                    const int cx = min(max(ix + k - 3, 0), Ww - 1);
                    h = fmaf(s_f[fx][k], rp[cx], h);
                }
                vx[u] = h;
            }
        }
    }

    float* o0 = op + (size_t)oy0 * OWw + 4u * g;
    int rs = 0;
    if (!(s_rm[0] & 0x4000u)) {      // block-uniform: only the oy0==0 block enters
        while (rs < RPB && !(s_rm[rs] & 0x4000u)) ++rs;
        for (int r = 0; r < rs; ++r) {
            const unsigned rm = s_rm[r];
            const int fy = (int)((rm >> 10) & 15u);
            const int iy = (int)((rm >> 15) & 8191u) - 8;
            float vals[4];
            #pragma unroll
            for (int u = 0; u < 4; ++u) {
                float acc = 0.f;
                #pragma unroll
                for (int j = 0; j < 8; ++j) {
                    const int ry = min(max(iy + j - 3, 0), Hh - 1);
                    const float* __restrict__ rp2 = xp + ry * Ww;
                    float h = 0.f;
                    #pragma unroll
                    for (int k = 0; k < 8; ++k) {
                        const int cx = min(max(ixs[u] + k - 3, 0), Ww - 1);
                        h = fmaf(s_f[fxs[u]][k], rp2[cx], h);
                    }
                    acc = fmaf(s_f[fy][j], h, acc);
                }
                vals[u] = acc * inv;
            }
            floatx4 v = { vals[0], vals[1], vals[2], vals[3] };
            *reinterpret_cast<floatx4*>(o0 + (size_t)r * OWw) = v;
        }
    }

    // ---- Saturated rows: preload weights to registers, fully unrolled stores ----
    float wy[RPB];
    #pragma unroll
    for (int r = 0; r < RPB; ++r) wy[r] = s_wy[r];
    float* o = o0 + (size_t)rs * OWw;
    for (int r = rs; r < RPB; ++r) {
        const float w = wy[r];
        floatx4 v = { vx[0] * w, vx[1] * w, vx[2] * w, vx[3] * w };
        *reinterpret_cast<floatx4*>(o) = v;
        o += OWw;
    }
}

extern "C" void kernel_launch(void* const* d_in, const int* in_sizes, int n_in,
                              void* d_out, int out_size, void* d_ws, size_t ws_size,
                              hipStream_t stream) {
    const float* x       = (const float*)d_in[0];
    const float* filt    = (const float*)d_in[1];
    const int*   scale_p = (const int*)d_in[2];
    float* out = (float*)d_out;
    dim3 grid(3, OHh / RPB, 16), block(256);   // 3 col-tiles x 27 row-chunks x 16 images
    vtm_upsample<<<grid, block, 0, stream>>>(x, filt, scale_p, out);
}

// Round 9
// 321.457 us; speedup vs baseline: 1.2324x; 1.2324x over previous
//
#include <hip/hip_runtime.h>

// x[2,8,540,960] f32, filt[16,8] f32, scale=3 (runtime), out[2,8,1620,2880] f32.
#define Hh 540
#define Ww 960
#define OHh 1620
#define OWw 2880
#define OW4 720          // float4 groups per output row
#define RPB 30           // rows per block; 1620 = 54 * 30

typedef float floatx4 __attribute__((ext_vector_type(4)));

// Thread owns 4 fixed output columns; loops over RPB rows. Row-invariant work
// (column phases, x loads, horizontal collapse) hoisted out of the row loop.
// Fully-saturated blocks (all but oy0==0) take a statically-unrolled path:
// 30x {4 mults + coalesced 16B store} per thread.
__global__ __launch_bounds__(256) void vtm_upsample(
    const float* __restrict__ x, const float* __restrict__ filt,
    const int* __restrict__ scale_p, float* __restrict__ out)
{
    __shared__ float s_f[16][8];
    __shared__ float s_sum[16];
    __shared__ float s_wy[RPB];      // s_sum[fy] * (1/4096) per row
    __shared__ unsigned s_rm[RPB];   // r0 | fy<<10 | sat<<14 | (iy+8)<<15

    const int tid = threadIdx.x;
    const unsigned scale = (unsigned)*scale_p;
    const float inv = 1.0f / 4096.0f;
    const unsigned oy0 = blockIdx.y * RPB;

    if (tid < 128) ((float*)s_f)[tid] = filt[tid];
    __syncthreads();
    if (tid < 16) {
        float s = 0.f;
        #pragma unroll
        for (int k = 0; k < 8; ++k) s += s_f[tid][k];  // same order as prior passing rounds
        s_sum[tid] = s;
    }
    __syncthreads();
    if (tid < RPB) {
        // Row phase: ref=int(oy*16384/scale); integer=ref>>4; frac=ref&15 (u32 math).
        const unsigned oy = oy0 + (unsigned)tid;
        const unsigned ref = (oy * 16384u) / scale;
        const int ii = (int)(ref >> 4);
        const unsigned f = ref & 15u;
        const int lo = min(max(ii - 3, 0), Hh - 1);
        const int hi = min(max(ii + 4, 0), Hh - 1);
        s_rm[tid] = (unsigned)lo | (f << 10) | ((lo == hi) ? 0x4000u : 0u)
                  | ((unsigned)(min(max(ii, -8), 4095) + 8) << 15);
        s_wy[tid] = s_sum[f] * inv;
    }
    __syncthreads();

    const unsigned bc = blockIdx.z;
    const float* __restrict__ xp = x + (size_t)bc * (Hh * Ww);
    float* __restrict__ op = out + (size_t)bc * ((size_t)OHh * OWw);
    const unsigned g = blockIdx.x * 256u + (unsigned)tid;
    if (g >= OW4) return;            // no barriers below this point

    // ---- Row-invariant column setup (once per thread) ----
    float vx[4];                     // row-H-1-collapsed value * wx (saturated rows)
    int   ixs[4], fxs[4];
    {
        const float* __restrict__ rp = xp + (Hh - 1) * Ww;
        #pragma unroll
        for (int u = 0; u < 4; ++u) {
            const unsigned ox = 4u * g + (unsigned)u;
            const unsigned refx = (ox * 16384u) / scale;
            const int ix = (int)(refx >> 4);
            const int fx = (int)(refx & 15u);
            ixs[u] = ix; fxs[u] = fx;
            const int c0 = min(max(ix - 3, 0), Ww - 1);
            const int c7 = min(max(ix + 4, 0), Ww - 1);
            if (c0 == c7) {
                vx[u] = rp[c0] * s_sum[fx];            // horizontal 8-tap collapses
            } else {
                float h = 0.f;                          // rare: ox<3 — real horizontal MAC
                #pragma unroll
                for (int k = 0; k < 8; ++k) {
                    const int cx = min(max(ix + k - 3, 0), Ww - 1);
                    h = fmaf(s_f[fx][k], rp[cx], h);
                }
                vx[u] = h;
            }
        }
    }

    float* o0 = op + (size_t)oy0 * OWw + 4u * g;

    if (s_rm[0] & 0x4000u) {
        // ---- Fully saturated block (2591/2592 blocks): static unroll, static
        // register indices — no runtime-bounded loops, no scratch. ----
        float wy[RPB];
        #pragma unroll
        for (int r = 0; r < RPB; ++r) wy[r] = s_wy[r];
        #pragma unroll
        for (int r = 0; r < RPB; ++r) {
            const float w = wy[r];
            floatx4 v = { vx[0] * w, vx[1] * w, vx[2] * w, vx[3] * w };
            *reinterpret_cast<floatx4*>(o0 + (size_t)r * OWw) = v;
        }
    } else {
        // ---- oy0==0 block: non-saturated prefix (oy<2 for scale=3), general MAC ----
        int rs = 0;
        while (rs < RPB && !(s_rm[rs] & 0x4000u)) ++rs;
        for (int r = 0; r < rs; ++r) {
            const unsigned rm = s_rm[r];
            const int fy = (int)((rm >> 10) & 15u);
            const int iy = (int)((rm >> 15) & 8191u) - 8;
            float vals[4];
            #pragma unroll
            for (int u = 0; u < 4; ++u) {
                float acc = 0.f;
                #pragma unroll
                for (int j = 0; j < 8; ++j) {
                    const int ry = min(max(iy + j - 3, 0), Hh - 1);
                    const float* __restrict__ rp2 = xp + ry * Ww;
                    float h = 0.f;
                    #pragma unroll
                    for (int k = 0; k < 8; ++k) {
                        const int cx = min(max(ixs[u] + k - 3, 0), Ww - 1);
                        h = fmaf(s_f[fxs[u]][k], rp2[cx], h);
                    }
                    acc = fmaf(s_f[fy][j], h, acc);
                }
                vals[u] = acc * inv;
            }
            floatx4 v = { vals[0], vals[1], vals[2], vals[3] };
            *reinterpret_cast<floatx4*>(o0 + (size_t)r * OWw) = v;
        }
        // Saturated remainder via LDS-read loop (runs once per image; cold path).
        for (int r = rs; r < RPB; ++r) {
            const float w = s_wy[r];
            floatx4 v = { vx[0] * w, vx[1] * w, vx[2] * w, vx[3] * w };
            *reinterpret_cast<floatx4*>(o0 + (size_t)r * OWw) = v;
        }
    }
}

extern "C" void kernel_launch(void* const* d_in, const int* in_sizes, int n_in,
                              void* d_out, int out_size, void* d_ws, size_t ws_size,
                              hipStream_t stream) {
    const float* x       = (const float*)d_in[0];
    const float* filt    = (const float*)d_in[1];
    const int*   scale_p = (const int*)d_in[2];
    float* out = (float*)d_out;
    dim3 grid(3, OHh / RPB, 16), block(256);   // 3 col-tiles x 54 row-chunks x 16 images
    vtm_upsample<<<grid, block, 0, stream>>>(x, filt, scale_p, out);
}